// Round 1
// baseline (9052.068 us; speedup 1.0000x reference)
//
#include <hip/hip_runtime.h>
#include <math.h>

#define NN 512
#define DD 8192

// ---------------- row-norm scales: scale[m][r] = 1 / max(||row||, 1e-6) ----------------
__global__ __launch_bounds__(256) void norm_kernel(
    const float* __restrict__ a0, const float* __restrict__ a1,
    const float* __restrict__ a2, float* __restrict__ scales) {
  const float* mats[3] = {a0, a1, a2};
  const int m = blockIdx.y;
  const int row = blockIdx.x;
  const float* x = mats[m] + (size_t)row * DD;
  const int tid = threadIdx.x;
  float s = 0.f;
  for (int k = tid * 4; k < DD; k += 256 * 4) {
    const float4 v = *(const float4*)(x + k);
    s += v.x * v.x + v.y * v.y + v.z * v.z + v.w * v.w;
  }
#pragma unroll
  for (int off = 32; off > 0; off >>= 1) s += __shfl_down(s, off);
  __shared__ float ws[4];
  if ((tid & 63) == 0) ws[tid >> 6] = s;
  __syncthreads();
  if (tid == 0) {
    const float t = ws[0] + ws[1] + ws[2] + ws[3];
    scales[m * NN + row] = 1.0f / fmaxf(sqrtf(t), 1e-6f);
  }
}

// ---------------- cost_p = 1 - (A B^T) * sa * sb, p: (0:1->2, 1:2->3, 2:3->1) ----------
__global__ __launch_bounds__(256) void cost_gemm_kernel(
    const float* __restrict__ a0, const float* __restrict__ a1,
    const float* __restrict__ a2, const float* __restrict__ scales,
    float* __restrict__ cost_all) {
  const float* mats[3] = {a0, a1, a2};
  const int p = blockIdx.z;
  const int pA = p, pB = (p + 1) % 3;
  const float* A = mats[pA];
  const float* B = mats[pB];
  float* C = cost_all + (size_t)p * NN * NN;

  __shared__ float lds_a[32 * 64];
  __shared__ float lds_b[32 * 64];

  const int tid = threadIdx.x;
  const int rowBase = blockIdx.y * 64;
  const int colBase = blockIdx.x * 64;

  const int lr = tid & 63;   // row within tile for staging
  const int lq = tid >> 6;   // 0..3

  const float* Arow = A + (size_t)(rowBase + lr) * DD;
  const float* Brow = B + (size_t)(colBase + lr) * DD;

  float acc[4][4];
#pragma unroll
  for (int i = 0; i < 4; ++i)
#pragma unroll
    for (int j = 0; j < 4; ++j) acc[i][j] = 0.f;

  const int tx = tid & 15, ty = tid >> 4;

  for (int kb = 0; kb < DD; kb += 32) {
#pragma unroll
    for (int qq = 0; qq < 2; ++qq) {
      const int q = lq + qq * 4;  // 0..7, covers k offsets q*4..q*4+3
      const float4 av = *(const float4*)(Arow + kb + q * 4);
      const float4 bv = *(const float4*)(Brow + kb + q * 4);
      lds_a[(q * 4 + 0) * 64 + lr] = av.x;
      lds_a[(q * 4 + 1) * 64 + lr] = av.y;
      lds_a[(q * 4 + 2) * 64 + lr] = av.z;
      lds_a[(q * 4 + 3) * 64 + lr] = av.w;
      lds_b[(q * 4 + 0) * 64 + lr] = bv.x;
      lds_b[(q * 4 + 1) * 64 + lr] = bv.y;
      lds_b[(q * 4 + 2) * 64 + lr] = bv.z;
      lds_b[(q * 4 + 3) * 64 + lr] = bv.w;
    }
    __syncthreads();
#pragma unroll
    for (int k = 0; k < 32; ++k) {
      const float4 a4 = *(const float4*)(&lds_a[k * 64 + ty * 4]);
      const float4 b4 = *(const float4*)(&lds_b[k * 64 + tx * 4]);
      const float as0[4] = {a4.x, a4.y, a4.z, a4.w};
      const float bs0[4] = {b4.x, b4.y, b4.z, b4.w};
#pragma unroll
      for (int ii = 0; ii < 4; ++ii)
#pragma unroll
        for (int jj = 0; jj < 4; ++jj)
          acc[ii][jj] = fmaf(as0[ii], bs0[jj], acc[ii][jj]);
    }
    __syncthreads();
  }

#pragma unroll
  for (int ii = 0; ii < 4; ++ii) {
    const int gr = rowBase + ty * 4 + ii;
    const float sa = scales[pA * NN + gr];
#pragma unroll
    for (int jj = 0; jj < 4; ++jj) {
      const int gc = colBase + tx * 4 + jj;
      const float sb = scales[pB * NN + gc];
      C[gr * NN + gc] = 1.0f - acc[ii][jj] * sa * sb;
    }
  }
}

// ---------------- exact JV shortest-augmenting-path LAP, ONE WAVE per problem ----------
// 64 lanes, lane t owns columns/rows 8t..8t+7. All uniform state in registers;
// no barriers inside the augmenting-path loop (wave-synchronous shuffles only).
// float64 duals, identical op order to reference solve_lap_np.

// bijective LDS index swizzle so owner-lane writes (stride 8 doubles) are bank-conflict-free
__device__ __forceinline__ int SW(int c) { return ((c & 7) << 6) | (c >> 3); }

__global__ __launch_bounds__(64) void lap_kernel(
    const float* __restrict__ cost_all, float* __restrict__ out) {
  const int p = blockIdx.x;
  const float* cost = cost_all + (size_t)p * NN * NN;
  float* outp = out + (size_t)p * NN * NN;
  const int tid = threadIdx.x;  // 0..63

  __shared__ double sh_u[NN];        // u[row], stored at SW(row)
  __shared__ double sh_shortest[NN]; // shortest[col], stored at SW(col)
  __shared__ int sh_path[NN];        // path[col], stored at SW(col)
  __shared__ int sh_col4row[NN];     // col4row[row], stored at SW(row)
  __shared__ int sh_row4col[NN];     // row4col[col], stored at SW(col)

  const double INF = __builtin_inf();

  for (int k = tid; k < NN; k += 64) {
    sh_u[k] = 0.0;
    sh_col4row[k] = -1;
    sh_row4col[k] = -1;
  }
  double myV[8];
#pragma unroll
  for (int q = 0; q < 8; ++q) myV[q] = 0.0;  // v[8*tid+q], owner-only
  __syncthreads();

  for (int cur_row = 0; cur_row < NN; ++cur_row) {
    double mySh[8];
#pragma unroll
    for (int q = 0; q < 8; ++q) mySh[q] = INF;
    unsigned int scMask = 0;  // SC bits for owned cols
    unsigned int srMask = 0;  // SR bits for owned rows
    int i = cur_row;          // uniform
    double minv = 0.0;        // uniform
    int sink = -1;            // uniform

    while (sink < 0) {
      if ((i >> 3) == tid) srMask |= 1u << (i & 7);
      const double u_i = sh_u[SW(i)];  // broadcast read
      const float4 c0 = *(const float4*)(cost + (size_t)i * NN + tid * 8);
      const float4 c1 = *(const float4*)(cost + (size_t)i * NN + tid * 8 + 4);
      const float cf[8] = {c0.x, c0.y, c0.z, c0.w, c1.x, c1.y, c1.z, c1.w};
#pragma unroll
      for (int q = 0; q < 8; ++q) {
        if (!(scMask & (1u << q))) {
          const double r = minv + (double)cf[q] - u_i - myV[q];
          if (r < mySh[q]) {
            mySh[q] = r;
            sh_shortest[SW(tid * 8 + q)] = r;  // write-through for dual updates
            sh_path[SW(tid * 8 + q)] = i;
          }
        }
      }
      // per-lane argmin over non-SC cols (strict < keeps smallest q on ties)
      double val = INF;
      int qbest = 0;
#pragma unroll
      for (int q = 0; q < 8; ++q) {
        if (!(scMask & (1u << q)) && mySh[q] < val) { val = mySh[q]; qbest = q; }
      }
      // wave min (value-only butterfly)
      double bval = val;
#pragma unroll
      for (int off = 32; off > 0; off >>= 1) {
        const double o = __shfl_xor(bval, off);
        bval = fmin(bval, o);
      }
      // smallest lane holding the min  ->  smallest global column index
      const unsigned long long m = __ballot(val == bval);
      const int srcLane = __ffsll(m) - 1;
      const int bj = __shfl(qbest, srcLane) + srcLane * 8;  // uniform
      minv = bval;
      if (srcLane == tid) scMask |= 1u << qbest;
      const int r4c = sh_row4col[SW(bj)];  // broadcast read
      if (r4c < 0) sink = bj; else i = r4c;
    }

    __syncthreads();  // publish sh_shortest / sh_path
    // dual updates (before augmentation, matching reference)
#pragma unroll
    for (int q = 0; q < 8; ++q) {
      const int row = tid * 8 + q;
      if (row == cur_row) {
        sh_u[SW(row)] += minv;
      } else if (srMask & (1u << q)) {
        sh_u[SW(row)] += minv - sh_shortest[SW(sh_col4row[SW(row)])];
      }
      if (scMask & (1u << q)) myV[q] -= minv - mySh[q];
    }
    __syncthreads();  // dual reads of pre-augment col4row complete
    // augment along the alternating path (short chain, lane 0)
    if (tid == 0) {
      int j = sink;
      while (true) {
        const int pi = sh_path[SW(j)];
        sh_row4col[SW(j)] = pi;
        const int tmp = sh_col4row[SW(pi)];
        sh_col4row[SW(pi)] = j;
        j = tmp;
        if (pi == cur_row) break;
      }
    }
    __syncthreads();  // publish matching for next phase
  }

#pragma unroll
  for (int q = 0; q < 8; ++q) {
    const int row = tid * 8 + q;
    outp[(size_t)row * NN + sh_col4row[SW(row)]] = 1.0f;
  }
}

extern "C" void kernel_launch(void* const* d_in, const int* in_sizes, int n_in,
                              void* d_out, int out_size, void* d_ws, size_t ws_size,
                              hipStream_t stream) {
  const float* un1 = (const float*)d_in[0];
  const float* un2 = (const float*)d_in[1];
  const float* un3 = (const float*)d_in[2];
  float* out = (float*)d_out;

  float* cost = (float*)d_ws;                       // 3 * 512 * 512 floats
  float* scales = cost + (size_t)3 * NN * NN;       // 3 * 512 floats

  hipMemsetAsync(d_out, 0, (size_t)out_size * sizeof(float), stream);

  norm_kernel<<<dim3(NN, 3), 256, 0, stream>>>(un1, un2, un3, scales);
  cost_gemm_kernel<<<dim3(NN / 64, NN / 64, 3), 256, 0, stream>>>(un1, un2, un3, scales, cost);
  lap_kernel<<<3, 64, 0, stream>>>(cost, out);
}

// Round 2
// 8192.517 us; speedup vs baseline: 1.1049x; 1.1049x over previous
//
#include <hip/hip_runtime.h>
#include <math.h>

#define NN 512
#define DD 8192

// ---------------- row-norm scales: scale[m][r] = 1 / max(||row||, 1e-6) ----------------
__global__ __launch_bounds__(256) void norm_kernel(
    const float* __restrict__ a0, const float* __restrict__ a1,
    const float* __restrict__ a2, float* __restrict__ scales) {
  const float* mats[3] = {a0, a1, a2};
  const int m = blockIdx.y;
  const int row = blockIdx.x;
  const float* x = mats[m] + (size_t)row * DD;
  const int tid = threadIdx.x;
  float s = 0.f;
  for (int k = tid * 4; k < DD; k += 256 * 4) {
    const float4 v = *(const float4*)(x + k);
    s += v.x * v.x + v.y * v.y + v.z * v.z + v.w * v.w;
  }
#pragma unroll
  for (int off = 32; off > 0; off >>= 1) s += __shfl_down(s, off);
  __shared__ float ws[4];
  if ((tid & 63) == 0) ws[tid >> 6] = s;
  __syncthreads();
  if (tid == 0) {
    const float t = ws[0] + ws[1] + ws[2] + ws[3];
    scales[m * NN + row] = 1.0f / fmaxf(sqrtf(t), 1e-6f);
  }
}

// ---------------- cost_p = 1 - (A B^T) * sa * sb, p: (0:1->2, 1:2->3, 2:3->1) ----------
__global__ __launch_bounds__(256) void cost_gemm_kernel(
    const float* __restrict__ a0, const float* __restrict__ a1,
    const float* __restrict__ a2, const float* __restrict__ scales,
    float* __restrict__ cost_all) {
  const float* mats[3] = {a0, a1, a2};
  const int p = blockIdx.z;
  const int pA = p, pB = (p + 1) % 3;
  const float* A = mats[pA];
  const float* B = mats[pB];
  float* C = cost_all + (size_t)p * NN * NN;

  __shared__ float lds_a[32 * 64];
  __shared__ float lds_b[32 * 64];

  const int tid = threadIdx.x;
  const int rowBase = blockIdx.y * 64;
  const int colBase = blockIdx.x * 64;

  const int lr = tid & 63;   // row within tile for staging
  const int lq = tid >> 6;   // 0..3

  const float* Arow = A + (size_t)(rowBase + lr) * DD;
  const float* Brow = B + (size_t)(colBase + lr) * DD;

  float acc[4][4];
#pragma unroll
  for (int i = 0; i < 4; ++i)
#pragma unroll
    for (int j = 0; j < 4; ++j) acc[i][j] = 0.f;

  const int tx = tid & 15, ty = tid >> 4;

  for (int kb = 0; kb < DD; kb += 32) {
#pragma unroll
    for (int qq = 0; qq < 2; ++qq) {
      const int q = lq + qq * 4;  // 0..7, covers k offsets q*4..q*4+3
      const float4 av = *(const float4*)(Arow + kb + q * 4);
      const float4 bv = *(const float4*)(Brow + kb + q * 4);
      lds_a[(q * 4 + 0) * 64 + lr] = av.x;
      lds_a[(q * 4 + 1) * 64 + lr] = av.y;
      lds_a[(q * 4 + 2) * 64 + lr] = av.z;
      lds_a[(q * 4 + 3) * 64 + lr] = av.w;
      lds_b[(q * 4 + 0) * 64 + lr] = bv.x;
      lds_b[(q * 4 + 1) * 64 + lr] = bv.y;
      lds_b[(q * 4 + 2) * 64 + lr] = bv.z;
      lds_b[(q * 4 + 3) * 64 + lr] = bv.w;
    }
    __syncthreads();
#pragma unroll
    for (int k = 0; k < 32; ++k) {
      const float4 a4 = *(const float4*)(&lds_a[k * 64 + ty * 4]);
      const float4 b4 = *(const float4*)(&lds_b[k * 64 + tx * 4]);
      const float as0[4] = {a4.x, a4.y, a4.z, a4.w};
      const float bs0[4] = {b4.x, b4.y, b4.z, b4.w};
#pragma unroll
      for (int ii = 0; ii < 4; ++ii)
#pragma unroll
        for (int jj = 0; jj < 4; ++jj)
          acc[ii][jj] = fmaf(as0[ii], bs0[jj], acc[ii][jj]);
    }
    __syncthreads();
  }

#pragma unroll
  for (int ii = 0; ii < 4; ++ii) {
    const int gr = rowBase + ty * 4 + ii;
    const float sa = scales[pA * NN + gr];
#pragma unroll
    for (int jj = 0; jj < 4; ++jj) {
      const int gc = colBase + tx * 4 + jj;
      const float sb = scales[pB * NN + gc];
      C[gr * NN + gc] = 1.0f - acc[ii][jj] * sa * sb;
    }
  }
}

// ---------------- exact JV shortest-augmenting-path LAP, ONE WAVE per problem ----------
// Lane t owns columns/rows 8t..8t+7. Cross-lane argmin via DPP (VALU latency), not
// ds_bpermute. row4col carried through the reduce as a payload (phase-constant).
// float64 duals, op order identical to reference solve_lap_np.

// bijective LDS index swizzle: owner-lane accesses (stride 8) become conflict-free
__device__ __forceinline__ int SW(int c) { return ((c & 7) << 6) | (c >> 3); }

// full-wave (64-lane) u32 min via DPP; returns broadcast scalar
__device__ __forceinline__ unsigned wave_min_u32(unsigned x) {
  int t;
  t = __builtin_amdgcn_update_dpp((int)x, (int)x, 0x111, 0xf, 0xf, false);  // row_shr:1
  x = ((unsigned)t < x) ? (unsigned)t : x;
  t = __builtin_amdgcn_update_dpp((int)x, (int)x, 0x112, 0xf, 0xf, false);  // row_shr:2
  x = ((unsigned)t < x) ? (unsigned)t : x;
  t = __builtin_amdgcn_update_dpp((int)x, (int)x, 0x114, 0xf, 0xf, false);  // row_shr:4
  x = ((unsigned)t < x) ? (unsigned)t : x;
  t = __builtin_amdgcn_update_dpp((int)x, (int)x, 0x118, 0xf, 0xf, false);  // row_shr:8
  x = ((unsigned)t < x) ? (unsigned)t : x;
  t = __builtin_amdgcn_update_dpp((int)x, (int)x, 0x142, 0xf, 0xf, false);  // row_bcast:15
  x = ((unsigned)t < x) ? (unsigned)t : x;
  t = __builtin_amdgcn_update_dpp((int)x, (int)x, 0x143, 0xf, 0xf, false);  // row_bcast:31
  x = ((unsigned)t < x) ? (unsigned)t : x;
  return (unsigned)__builtin_amdgcn_readlane((int)x, 63);
}

__global__ __launch_bounds__(64) void lap_kernel(
    const float* __restrict__ cost_all, float* __restrict__ out) {
  const int p = blockIdx.x;
  const float* cost = cost_all + (size_t)p * NN * NN;
  float* outp = out + (size_t)p * NN * NN;
  const int tid = threadIdx.x;  // 0..63

  __shared__ double sh_u[NN];        // u[row] at SW(row)
  __shared__ double sh_shortest[NN]; // shortest[col] at SW(col)
  __shared__ int sh_path[NN];        // path[col] at SW(col)
  __shared__ int sh_col4row[NN];     // col4row[row] at SW(row)
  __shared__ int sh_row4col[NN];     // row4col[col] at SW(col)

  const double INF = __builtin_inf();

  for (int k = tid; k < NN; k += 64) {
    sh_u[k] = 0.0;
    sh_col4row[k] = -1;
    sh_row4col[k] = -1;
  }
  double myV[8];
#pragma unroll
  for (int q = 0; q < 8; ++q) myV[q] = 0.0;  // v[8*tid+q], owner-only
  __syncthreads();

  for (int cur_row = 0; cur_row < NN; ++cur_row) {
    double mySh[8];   // frozen-at-SC shortest values (for dual updates)
    double selv[8];   // candidate values for argmin (INF once in SC)
    unsigned pl[8];   // payload: (q<<10) | (row4col[col]+1)   (phase-constant)
#pragma unroll
    for (int q = 0; q < 8; ++q) { mySh[q] = INF; selv[q] = INF; }
#pragma unroll
    for (int q = 0; q < 8; ++q)
      pl[q] = ((unsigned)q << 10) | (unsigned)(sh_row4col[SW(tid * 8 + q)] + 1);

    unsigned scMask = 0, srMask = 0;
    int i = cur_row;     // uniform
    double minv = 0.0;   // uniform
    int sink = -1;       // uniform

    while (sink < 0) {
      if ((i >> 3) == tid) srMask |= 1u << (i & 7);
      const double u_i = sh_u[SW(i)];  // overlaps the cost-row load below
      const float4 c0 = *(const float4*)(cost + (size_t)i * NN + tid * 8);
      const float4 c1 = *(const float4*)(cost + (size_t)i * NN + tid * 8 + 4);
      const float cf[8] = {c0.x, c0.y, c0.z, c0.w, c1.x, c1.y, c1.z, c1.w};
#pragma unroll
      for (int q = 0; q < 8; ++q) {
        if (!(scMask & (1u << q))) {
          const double r = minv + (double)cf[q] - u_i - myV[q];  // ((minv+c)-u)-v
          if (r < mySh[q]) {
            mySh[q] = r;
            selv[q] = r;
            sh_shortest[SW(tid * 8 + q)] = r;  // write-through for dual updates
            sh_path[SW(tid * 8 + q)] = i;
          }
        }
      }
      // per-lane tournament over 8 candidates (ties keep lowest q)
      const bool t01 = selv[1] < selv[0];
      double v01 = t01 ? selv[1] : selv[0]; unsigned p01 = t01 ? pl[1] : pl[0];
      const bool t23 = selv[3] < selv[2];
      double v23 = t23 ? selv[3] : selv[2]; unsigned p23 = t23 ? pl[3] : pl[2];
      const bool t45 = selv[5] < selv[4];
      double v45 = t45 ? selv[5] : selv[4]; unsigned p45 = t45 ? pl[5] : pl[4];
      const bool t67 = selv[7] < selv[6];
      double v67 = t67 ? selv[7] : selv[6]; unsigned p67 = t67 ? pl[7] : pl[6];
      const bool ta = v23 < v01;
      double vab = ta ? v23 : v01; unsigned pab = ta ? p23 : p01;
      const bool tb = v67 < v45;
      double vcd = tb ? v67 : v45; unsigned pcd = tb ? p67 : p45;
      const bool tc = vcd < vab;
      const double lv = tc ? vcd : vab; const unsigned lp = tc ? pcd : pab;
      // sortable u64 key (bijective, exact double ordering)
      const long long bb = __double_as_longlong(lv);
      const unsigned long long kk =
          (bb < 0) ? ~(unsigned long long)bb
                   : ((unsigned long long)bb | 0x8000000000000000ULL);
      const unsigned hi = (unsigned)(kk >> 32);
      const unsigned lo = (unsigned)kk;
      const unsigned minhi = wave_min_u32(hi);
      const unsigned lo2 = (hi == minhi) ? lo : 0xFFFFFFFFu;
      const unsigned minlo = wave_min_u32(lo2);
      const unsigned long long bal = __ballot(hi == minhi && lo == minlo);
      const int srcLane = __ffsll(bal) - 1;  // lowest lane = smallest column (tie-break)
      const unsigned pw = (unsigned)__builtin_amdgcn_readlane((int)lp, srcLane);
      const int qb = (int)(pw >> 10);
      const int r4 = (int)(pw & 0x3FFu) - 1;
      // reconstruct minv bit-exactly from the winning key
      const unsigned long long mk =
          ((unsigned long long)minhi << 32) | (unsigned long long)minlo;
      const long long mb = (mk >> 63) ? (long long)(mk & 0x7FFFFFFFFFFFFFFFULL)
                                      : (long long)~mk;
      minv = __longlong_as_double(mb);
      if (srcLane == tid) {
        scMask |= 1u << qb;
#pragma unroll
        for (int q = 0; q < 8; ++q)
          if (q == qb) selv[q] = INF;  // static index, predicated
      }
      if (r4 < 0) sink = srcLane * 8 + qb;
      else i = r4;
    }

    __syncthreads();  // publish sh_shortest / sh_path
    // dual updates (before augmentation, matching reference)
#pragma unroll
    for (int q = 0; q < 8; ++q) {
      const int row = tid * 8 + q;
      if (row == cur_row) {
        sh_u[SW(row)] += minv;
      } else if (srMask & (1u << q)) {
        sh_u[SW(row)] += minv - sh_shortest[SW(sh_col4row[SW(row)])];
      }
      if (scMask & (1u << q)) myV[q] -= minv - mySh[q];
    }
    __syncthreads();  // dual reads of pre-augment col4row complete
    // augment along the alternating path (short chain, lane 0)
    if (tid == 0) {
      int j = sink;
      while (true) {
        const int pi = sh_path[SW(j)];
        sh_row4col[SW(j)] = pi;
        const int tmp = sh_col4row[SW(pi)];
        sh_col4row[SW(pi)] = j;
        j = tmp;
        if (pi == cur_row) break;
      }
    }
    __syncthreads();  // publish matching for next phase
  }

#pragma unroll
  for (int q = 0; q < 8; ++q) {
    const int row = tid * 8 + q;
    outp[(size_t)row * NN + sh_col4row[SW(row)]] = 1.0f;
  }
}

extern "C" void kernel_launch(void* const* d_in, const int* in_sizes, int n_in,
                              void* d_out, int out_size, void* d_ws, size_t ws_size,
                              hipStream_t stream) {
  const float* un1 = (const float*)d_in[0];
  const float* un2 = (const float*)d_in[1];
  const float* un3 = (const float*)d_in[2];
  float* out = (float*)d_out;

  float* cost = (float*)d_ws;                       // 3 * 512 * 512 floats
  float* scales = cost + (size_t)3 * NN * NN;       // 3 * 512 floats

  hipMemsetAsync(d_out, 0, (size_t)out_size * sizeof(float), stream);

  norm_kernel<<<dim3(NN, 3), 256, 0, stream>>>(un1, un2, un3, scales);
  cost_gemm_kernel<<<dim3(NN / 64, NN / 64, 3), 256, 0, stream>>>(un1, un2, un3, scales, cost);
  lap_kernel<<<3, 64, 0, stream>>>(cost, out);
}

// Round 3
// 5734.963 us; speedup vs baseline: 1.5784x; 1.4285x over previous
//
#include <hip/hip_runtime.h>
#include <math.h>

#define NN 512
#define DD 8192

// ---------------- row-norm scales: scale[m][r] = 1 / max(||row||, 1e-6) ----------------
__global__ __launch_bounds__(256) void norm_kernel(
    const float* __restrict__ a0, const float* __restrict__ a1,
    const float* __restrict__ a2, float* __restrict__ scales) {
  const float* mats[3] = {a0, a1, a2};
  const int m = blockIdx.y;
  const int row = blockIdx.x;
  const float* x = mats[m] + (size_t)row * DD;
  const int tid = threadIdx.x;
  float s = 0.f;
  for (int k = tid * 4; k < DD; k += 256 * 4) {
    const float4 v = *(const float4*)(x + k);
    s += v.x * v.x + v.y * v.y + v.z * v.z + v.w * v.w;
  }
#pragma unroll
  for (int off = 32; off > 0; off >>= 1) s += __shfl_down(s, off);
  __shared__ float ws[4];
  if ((tid & 63) == 0) ws[tid >> 6] = s;
  __syncthreads();
  if (tid == 0) {
    const float t = ws[0] + ws[1] + ws[2] + ws[3];
    scales[m * NN + row] = 1.0f / fmaxf(sqrtf(t), 1e-6f);
  }
}

// ---------------- cost_p = 1 - (A B^T) * sa * sb, p: (0:1->2, 1:2->3, 2:3->1) ----------
__global__ __launch_bounds__(256) void cost_gemm_kernel(
    const float* __restrict__ a0, const float* __restrict__ a1,
    const float* __restrict__ a2, const float* __restrict__ scales,
    float* __restrict__ cost_all) {
  const float* mats[3] = {a0, a1, a2};
  const int p = blockIdx.z;
  const int pA = p, pB = (p + 1) % 3;
  const float* A = mats[pA];
  const float* B = mats[pB];
  float* C = cost_all + (size_t)p * NN * NN;

  __shared__ float lds_a[32 * 64];
  __shared__ float lds_b[32 * 64];

  const int tid = threadIdx.x;
  const int rowBase = blockIdx.y * 64;
  const int colBase = blockIdx.x * 64;

  const int lr = tid & 63;   // row within tile for staging
  const int lq = tid >> 6;   // 0..3

  const float* Arow = A + (size_t)(rowBase + lr) * DD;
  const float* Brow = B + (size_t)(colBase + lr) * DD;

  float acc[4][4];
#pragma unroll
  for (int i = 0; i < 4; ++i)
#pragma unroll
    for (int j = 0; j < 4; ++j) acc[i][j] = 0.f;

  const int tx = tid & 15, ty = tid >> 4;

  for (int kb = 0; kb < DD; kb += 32) {
#pragma unroll
    for (int qq = 0; qq < 2; ++qq) {
      const int q = lq + qq * 4;  // 0..7, covers k offsets q*4..q*4+3
      const float4 av = *(const float4*)(Arow + kb + q * 4);
      const float4 bv = *(const float4*)(Brow + kb + q * 4);
      lds_a[(q * 4 + 0) * 64 + lr] = av.x;
      lds_a[(q * 4 + 1) * 64 + lr] = av.y;
      lds_a[(q * 4 + 2) * 64 + lr] = av.z;
      lds_a[(q * 4 + 3) * 64 + lr] = av.w;
      lds_b[(q * 4 + 0) * 64 + lr] = bv.x;
      lds_b[(q * 4 + 1) * 64 + lr] = bv.y;
      lds_b[(q * 4 + 2) * 64 + lr] = bv.z;
      lds_b[(q * 4 + 3) * 64 + lr] = bv.w;
    }
    __syncthreads();
#pragma unroll
    for (int k = 0; k < 32; ++k) {
      const float4 a4 = *(const float4*)(&lds_a[k * 64 + ty * 4]);
      const float4 b4 = *(const float4*)(&lds_b[k * 64 + tx * 4]);
      const float as0[4] = {a4.x, a4.y, a4.z, a4.w};
      const float bs0[4] = {b4.x, b4.y, b4.z, b4.w};
#pragma unroll
      for (int ii = 0; ii < 4; ++ii)
#pragma unroll
        for (int jj = 0; jj < 4; ++jj)
          acc[ii][jj] = fmaf(as0[ii], bs0[jj], acc[ii][jj]);
    }
    __syncthreads();
  }

#pragma unroll
  for (int ii = 0; ii < 4; ++ii) {
    const int gr = rowBase + ty * 4 + ii;
    const float sa = scales[pA * NN + gr];
#pragma unroll
    for (int jj = 0; jj < 4; ++jj) {
      const int gc = colBase + tx * 4 + jj;
      const float sb = scales[pB * NN + gc];
      C[gr * NN + gc] = 1.0f - acc[ii][jj] * sa * sb;
    }
  }
}

// ---------------- exact JV shortest-augmenting-path LAP, ONE WAVE per problem ----------
// Lane t owns columns/rows 8t..8t+7. Zero LDS ops in the inner loop: path/frozen
// shortest live in registers (frozen value of a column == minv at its SC-add time),
// SC-exclusion via vAdj = -INF poison (r becomes +INF, compare auto-fails).
// float64 duals, op order identical to reference solve_lap_np.

// bijective LDS index swizzle: owner-lane accesses (stride 8) become conflict-free
__device__ __forceinline__ int SW(int c) { return ((c & 7) << 6) | (c >> 3); }

// full-wave (64-lane) u32 min via DPP; returns broadcast scalar
__device__ __forceinline__ unsigned wave_min_u32(unsigned x) {
  int t;
  t = __builtin_amdgcn_update_dpp((int)x, (int)x, 0x111, 0xf, 0xf, false);  // row_shr:1
  x = ((unsigned)t < x) ? (unsigned)t : x;
  t = __builtin_amdgcn_update_dpp((int)x, (int)x, 0x112, 0xf, 0xf, false);  // row_shr:2
  x = ((unsigned)t < x) ? (unsigned)t : x;
  t = __builtin_amdgcn_update_dpp((int)x, (int)x, 0x114, 0xf, 0xf, false);  // row_shr:4
  x = ((unsigned)t < x) ? (unsigned)t : x;
  t = __builtin_amdgcn_update_dpp((int)x, (int)x, 0x118, 0xf, 0xf, false);  // row_shr:8
  x = ((unsigned)t < x) ? (unsigned)t : x;
  t = __builtin_amdgcn_update_dpp((int)x, (int)x, 0x142, 0xf, 0xf, false);  // row_bcast:15
  x = ((unsigned)t < x) ? (unsigned)t : x;
  t = __builtin_amdgcn_update_dpp((int)x, (int)x, 0x143, 0xf, 0xf, false);  // row_bcast:31
  x = ((unsigned)t < x) ? (unsigned)t : x;
  return (unsigned)__builtin_amdgcn_readlane((int)x, 63);
}

__device__ __forceinline__ double readlane_f64(double x, int lane) {
  const long long b = __double_as_longlong(x);
  const int lo = __builtin_amdgcn_readlane((int)(b & 0xffffffffLL), lane);
  const int hi = __builtin_amdgcn_readlane((int)(b >> 32), lane);
  return __longlong_as_double(((long long)hi << 32) | (unsigned long long)(unsigned)lo);
}

__global__ __launch_bounds__(64) void lap_kernel(
    const float* __restrict__ cost_all, float* __restrict__ out) {
  const int p = blockIdx.x;
  const float* cost = cost_all + (size_t)p * NN * NN;
  float* outp = out + (size_t)p * NN * NN;
  const int tid = threadIdx.x;  // 0..63

  __shared__ double sh_u[NN];        // u[row] at SW(row)
  __shared__ double sh_shortest[NN]; // frozen shortest[col] at SW(col) (phase-end)
  __shared__ int sh_path[NN];        // path[col] at SW(col) (phase-end)
  __shared__ int sh_col4row[NN];     // col4row[row] at SW(row)
  __shared__ int sh_row4col[NN];     // row4col[col] at SW(col)

  const double INF = __builtin_inf();

  for (int k = tid; k < NN; k += 64) {
    sh_u[k] = 0.0;
    sh_col4row[k] = -1;
    sh_row4col[k] = -1;
  }
  double myV[8];
#pragma unroll
  for (int q = 0; q < 8; ++q) myV[q] = 0.0;  // v[8*tid+q], owner-only
  __syncthreads();

  for (int cur_row = 0; cur_row < NN; ++cur_row) {
    double selv[8];   // current shortest (INF once in SC); reduce input
    double vAdj[8];   // myV, poisoned to -INF when col enters SC
    double frz[8];    // frozen shortest at SC-add time (= minv then)
    int myPath[8];
    unsigned pl[8];   // payload: (q<<10) | (row4col[col]+1)  (phase-constant)
#pragma unroll
    for (int q = 0; q < 8; ++q) {
      selv[q] = INF;
      vAdj[q] = myV[q];
      frz[q] = 0.0;
      myPath[q] = 0;
    }
#pragma unroll
    for (int q = 0; q < 8; ++q)
      pl[q] = ((unsigned)q << 10) | (unsigned)(sh_row4col[SW(tid * 8 + q)] + 1);

    unsigned scMask = 0, srMask = 0;
    int i = cur_row;     // uniform
    double minv = 0.0;   // uniform
    int sink = -1;       // uniform
    int pendQ = -1, pendLane = 0;  // SC-add deferred into next iteration's load shadow

    while (true) {
      if ((i >> 3) == tid) srMask |= 1u << (i & 7);
      // issue the dependent loads FIRST; everything below hides in their shadow
      const float4 c0 = *(const float4*)(cost + (size_t)i * NN + tid * 8);
      const float4 c1 = *(const float4*)(cost + (size_t)i * NN + tid * 8 + 4);
      const double u_i = sh_u[SW(i)];  // LDS (~120cy) hides under global (~200cy)
      // apply previous iteration's SC-add (uniform pendQ -> scalar branches)
      if (pendQ >= 0) {
        const bool me = (tid == pendLane);
#define APPLY_SC(K)                                                     \
        if (pendQ == K) {                                               \
          if (me) {                                                     \
            selv[K] = INF; vAdj[K] = -INF; frz[K] = minv;               \
            scMask |= 1u << K;                                          \
          }                                                             \
        }
        APPLY_SC(0) APPLY_SC(1) APPLY_SC(2) APPLY_SC(3)
        APPLY_SC(4) APPLY_SC(5) APPLY_SC(6) APPLY_SC(7)
#undef APPLY_SC
      }
      const float cf[8] = {c0.x, c0.y, c0.z, c0.w, c1.x, c1.y, c1.z, c1.w};
      // f64 relax: reference order ((minv + c) - u_i) - v ; SC cols auto-fail (r=+INF)
#pragma unroll
      for (int q = 0; q < 8; ++q) {
        const double r = ((minv + (double)cf[q]) - u_i) - vAdj[q];
        const bool cnd = r < selv[q];
        selv[q] = fmin(selv[q], r);
        myPath[q] = cnd ? i : myPath[q];
      }
      // per-lane tournament over 8 candidates (ties keep lowest q)
      const bool t01 = selv[1] < selv[0];
      double v01 = t01 ? selv[1] : selv[0]; unsigned p01 = t01 ? pl[1] : pl[0];
      const bool t23 = selv[3] < selv[2];
      double v23 = t23 ? selv[3] : selv[2]; unsigned p23 = t23 ? pl[3] : pl[2];
      const bool t45 = selv[5] < selv[4];
      double v45 = t45 ? selv[5] : selv[4]; unsigned p45 = t45 ? pl[5] : pl[4];
      const bool t67 = selv[7] < selv[6];
      double v67 = t67 ? selv[7] : selv[6]; unsigned p67 = t67 ? pl[7] : pl[6];
      const bool ta = v23 < v01;
      const double vab = ta ? v23 : v01; const unsigned pab = ta ? p23 : p01;
      const bool tb = v67 < v45;
      const double vcd = tb ? v67 : v45; const unsigned pcd = tb ? p67 : p45;
      const bool tc = vcd < vab;
      const double lv = tc ? vcd : vab; const unsigned lp = tc ? pcd : pab;
      // sortable u64 key (bijective, exact double ordering)
      const long long bb = __double_as_longlong(lv);
      const unsigned long long kk =
          (bb < 0) ? ~(unsigned long long)bb
                   : ((unsigned long long)bb | 0x8000000000000000ULL);
      const unsigned hi = (unsigned)(kk >> 32);
      const unsigned lo = (unsigned)kk;
      const unsigned minhi = wave_min_u32(hi);
      unsigned long long bal = __ballot(hi == minhi);
      int srcLane;
      if (__popcll(bal) == 1) {  // unique hi-key => unique global min (common case)
        srcLane = __ffsll(bal) - 1;
      } else {
        const unsigned lo2 = (hi == minhi) ? lo : 0xFFFFFFFFu;
        const unsigned minlo = wave_min_u32(lo2);
        bal = __ballot((hi == minhi) && (lo == minlo));
        srcLane = __ffsll(bal) - 1;  // lowest lane = smallest column on exact ties
      }
      minv = readlane_f64(lv, srcLane);  // exact winning shortest value
      const unsigned pw = (unsigned)__builtin_amdgcn_readlane((int)lp, srcLane);
      const int qb = (int)(pw >> 10);
      const int r4 = (int)(pw & 0x3FFu) - 1;
      if (r4 < 0) {  // unmatched column: sink found (its SC-add is a dual no-op)
        sink = srcLane * 8 + qb;
        break;
      }
      i = r4;
      pendQ = qb;
      pendLane = srcLane;
    }

    // publish frozen shortest + path (only SC cols are ever read back)
#pragma unroll
    for (int q = 0; q < 8; ++q) {
      sh_shortest[SW(tid * 8 + q)] = frz[q];
      sh_path[SW(tid * 8 + q)] = myPath[q];
    }
    __syncthreads();
    // dual updates (before augmentation, matching reference)
#pragma unroll
    for (int q = 0; q < 8; ++q) {
      const int row = tid * 8 + q;
      if (row == cur_row) {
        sh_u[SW(row)] += minv;
      } else if (srMask & (1u << q)) {
        sh_u[SW(row)] += minv - sh_shortest[SW(sh_col4row[SW(row)])];
      }
      if (scMask & (1u << q)) myV[q] -= minv - frz[q];
    }
    __syncthreads();
    // augment along the alternating path (short chain, lane 0)
    if (tid == 0) {
      int j = sink;
      while (true) {
        const int pi = sh_path[SW(j)];
        sh_row4col[SW(j)] = pi;
        const int tmp = sh_col4row[SW(pi)];
        sh_col4row[SW(pi)] = j;
        j = tmp;
        if (pi == cur_row) break;
      }
    }
    __syncthreads();  // publish matching for next phase
  }

#pragma unroll
  for (int q = 0; q < 8; ++q) {
    const int row = tid * 8 + q;
    outp[(size_t)row * NN + sh_col4row[SW(row)]] = 1.0f;
  }
}

extern "C" void kernel_launch(void* const* d_in, const int* in_sizes, int n_in,
                              void* d_out, int out_size, void* d_ws, size_t ws_size,
                              hipStream_t stream) {
  const float* un1 = (const float*)d_in[0];
  const float* un2 = (const float*)d_in[1];
  const float* un3 = (const float*)d_in[2];
  float* out = (float*)d_out;

  float* cost = (float*)d_ws;                       // 3 * 512 * 512 floats
  float* scales = cost + (size_t)3 * NN * NN;       // 3 * 512 floats

  hipMemsetAsync(d_out, 0, (size_t)out_size * sizeof(float), stream);

  norm_kernel<<<dim3(NN, 3), 256, 0, stream>>>(un1, un2, un3, scales);
  cost_gemm_kernel<<<dim3(NN / 64, NN / 64, 3), 256, 0, stream>>>(un1, un2, un3, scales, cost);
  lap_kernel<<<3, 64, 0, stream>>>(cost, out);
}